// Round 1
// 124.910 us; speedup vs baseline: 1.0175x; 1.0175x over previous
//
#include <hip/hip_runtime.h>

// BLAMem: truncated tensor-algebra (depth 4, C=8) log-signature memory.
// 5 stream-ordered dispatches (kernel boundaries are the only cross-block sync).
// Round-8 restructure: kernel 1 stores the cumulative signature snapshot after each
// chunk (c=3 snapshot == group total), so kernel 3 no longer re-runs the Chen fold;
// it becomes a per-chunk (1024-block) apply+log+pool with P read straight into
// registers. Kernel 2 preloads its 64 scan operands per thread into registers.
// Carried lessons: NO device-scope atomics; all row-addressed LDS padded to stride 9.

#define MEM   4680   // 8 + 64 + 512 + 4096 (unpadded global layout)
#define NG    32     // groups per batch
#define TLEN  2048

// Padded LDS signature layout: L1 [0,8), L2 [8,72), L3 rows (i*8+j)*9+k at 72 (576),
// L4 rows ijk*9+l at 648 (4608). Total 5256 floats.
#define P3OFF 72
#define P4OFF 648
#define SIGSZ 5256

// Load the 64 per-step increments for group (b,g) into sInc[512].
__device__ __forceinline__ void load_inc(const float* __restrict__ x, int b, int g,
                                         float* sInc, int tid) {
    for (int e = tid; e < 512; e += 256) {
        int s = e >> 3, c = e & 7;
        int t = g * 64 + s;
        float v;
        if (c < 7) {
            float cur  = x[(b * TLEN + t) * 7 + c];
            float prev = (t > 0) ? x[(b * TLEN + t - 1) * 7 + c] : 0.f;
            v = cur - prev;
        } else v = (t > 0) ? (1.f / 2047.f) : 0.f;
        sInc[e] = v;
    }
}

// Fold chunk-local signature (16 steps, closed form) into running padded product sA.
// U scratch: loc3 padded 576 | loc2 64 | loc1 8 = 648 floats.
__device__ __forceinline__ void chunk_step(const float* dch, float* sA, float* U, int tid) {
    float* loc3 = U;
    float* loc2 = U + 576;
    float* loc1 = U + 640;
    const int i1 = tid >> 6, j1 = (tid >> 3) & 7, k1 = tid & 7;
    const int row1 = tid >> 3, row2 = row1 + 32;   // (i*8+j) for pos1/pos2
    const int jk = tid & 63;
    const int pos2 = tid + 256, i2 = pos2 >> 6;
    float p1a = 0.f, l2a = 0.f, l3a = 0.f, p1b = 0.f, l2b = 0.f, l3b = 0.f;
    float Sa[8], Sb[8];
#pragma unroll
    for (int l = 0; l < 8; l++) { Sa[l] = 0.f; Sb[l] = 0.f; }
#pragma unroll
    for (int t = 0; t < 16; t++) {
        const float* dr = dch + t * 8;
        float di1 = dr[i1], di2 = dr[i2], dj = dr[j1], dk = dr[k1];
        float ga = l3a + dk * (l2a * 0.5f + dj * (p1a * (1.f/6.f) + di1 * (1.f/24.f)));
        float gb = l3b + dk * (l2b * 0.5f + dj * (p1b * (1.f/6.f) + di2 * (1.f/24.f)));
#pragma unroll
        for (int l = 0; l < 8; l++) { float dv = dr[l]; Sa[l] += ga * dv; Sb[l] += gb * dv; }
        l3a += dk * (l2a + dj * (p1a * 0.5f + di1 * (1.f/6.f)));
        l3b += dk * (l2b + dj * (p1b * 0.5f + di2 * (1.f/6.f)));
        l2a += (p1a + di1 * 0.5f) * dj;
        l2b += (p1b + di2 * 0.5f) * dj;
        p1a += di1; p1b += di2;
    }
    loc3[row1 * 9 + k1] = l3a;
    loc3[row2 * 9 + k1] = l3b;
    if (k1 == 0) { loc2[row1] = l2a; loc2[row2] = l2b; }
    if (jk == 0) { loc1[i1] = p1a; loc1[i2] = p1b; }
    __syncthreads();
    float a1 = sA[i1], a2 = sA[8 + row1], a3 = sA[P3OFF + row1 * 9 + k1];
    float c1_ = sA[i2], c2_ = sA[8 + row2], c3_ = sA[P3OFF + row2 * 9 + k1];
    const float* l3p = &loc3[jk * 9];
    const float* l2p = &loc2[k1 * 8];
    float n4a[8], n4b[8];
#pragma unroll
    for (int l = 0; l < 8; l++) {
        float v3 = l3p[l], v2 = l2p[l], v1 = loc1[l];
        n4a[l] = sA[P4OFF + tid * 9 + l]  + Sa[l] + a1 * v3 + a2 * v2 + a3 * v1;
        n4b[l] = sA[P4OFF + pos2 * 9 + l] + Sb[l] + c1_ * v3 + c2_ * v2 + c3_ * v1;
    }
    float n3a = a3 + l3a + a1 * loc2[jk] + a2 * loc1[k1];
    float n3b = c3_ + l3b + c1_ * loc2[jk] + c2_ * loc1[k1];
    float n2v = 0.f, n1v = 0.f;
    if (tid < 64) n2v = sA[8 + tid] + loc2[tid] + sA[tid >> 3] * loc1[tid & 7];
    if (tid < 8)  n1v = sA[tid] + loc1[tid];
    __syncthreads();
#pragma unroll
    for (int l = 0; l < 8; l++) { sA[P4OFF + tid * 9 + l] = n4a[l]; sA[P4OFF + pos2 * 9 + l] = n4b[l]; }
    sA[P3OFF + row1 * 9 + k1] = n3a;
    sA[P3OFF + row2 * 9 + k1] = n3b;
    if (tid < 64) sA[8 + tid] = n2v;
    if (tid < 8)  sA[tid] = n1v;
    __syncthreads();
}

// ------------------------------------------------ kernel 1: per-chunk cumulative
// snapshots -> S[blk][c][MEM] (unpadded). c=3 snapshot doubles as the group total.
__global__ __launch_bounds__(256) void sig_totals_kernel(const float* __restrict__ x,
                                                         float* __restrict__ S) {
    int blk = blockIdx.x;
    int b = blk >> 5, g = blk & 31;
    int tid = threadIdx.x;

    __shared__ __attribute__((aligned(16))) float sInc[512];
    __shared__ __attribute__((aligned(16))) float sA[SIGSZ];
    __shared__ __attribute__((aligned(16))) float U[648];

    load_inc(x, b, g, sInc, tid);
    for (int m = tid; m < SIGSZ; m += 256) sA[m] = 0.f;
    __syncthreads();
    for (int c = 0; c < 4; c++) {
        chunk_step(&sInc[c * 128], sA, U, tid);
        // chunk_step ends with __syncthreads(); sA is stable until after the next
        // chunk_step's second barrier, so these reads are race-free.
        float* Sr = S + ((size_t)blk * 4 + c) * MEM;
        for (int m4 = tid * 4; m4 < MEM; m4 += 1024) {
            float4 v;
            if (m4 < 72) {
                v = make_float4(sA[m4], sA[m4 + 1], sA[m4 + 2], sA[m4 + 3]);
            } else if (m4 < 584) {
                int e = m4 - 72; const float* p0 = &sA[P3OFF + (e >> 3) * 9 + (e & 7)];
                v = make_float4(p0[0], p0[1], p0[2], p0[3]);
            } else {
                int e = m4 - 584; const float* p0 = &sA[P4OFF + (e >> 3) * 9 + (e & 7)];
                v = make_float4(p0[0], p0[1], p0[2], p0[3]);
            }
            *(float4*)(Sr + m4) = v;
        }
    }
}

// ------------------------------------------------ kernel 2: cascade scan (reads c=3
// snapshots as group totals) -> P (unpadded, exclusive group prefixes).
// Phase-C operands are preloaded into registers up front (64 independent coalesced
// loads issued before phases A/B run) so the 32-step scan is pure register/LDS work.
__global__ __launch_bounds__(256) void scan_fused_kernel(const float* __restrict__ S,
                                                         float* __restrict__ P) {
    int bx = blockIdx.x;
    int b = bx >> 4, s = bx & 15;
    int tid = threadIdx.x;

    __shared__ float st1[NG][8];
    __shared__ float st2[NG][64];
    __shared__ float st3[NG][32];
    __shared__ float sp1[NG][8];
    __shared__ float sp2[NG][64];
    __shared__ float sp3[NG][32];

    int bBase = b * NG;
    const int jkl   = ((s & 1) << 8) | tid;   // (s*256+tid) & 511
    const int m4idx = s * 256 + tid;          // this thread's L4 element

    float rL4[NG], rL3[NG];
#pragma unroll
    for (int g = 0; g < NG; g++) {
        const float* Trow = S + ((size_t)(bBase + g) * 4 + 3) * MEM;
        rL4[g] = Trow[584 + m4idx];
        rL3[g] = Trow[72 + jkl];
    }

    {
        int g = tid >> 3, i = tid & 7;
        st1[g][i] = S[((size_t)(bBase + g) * 4 + 3) * MEM + i];
    }
    for (int m = tid * 4; m < NG * 64; m += 1024) {
        int g = m >> 6, e = m & 63;
        *(float4*)&st2[g][e] = *(const float4*)(S + ((size_t)(bBase + g) * 4 + 3) * MEM + 8 + e);
    }
    for (int m = tid * 4; m < NG * 32; m += 1024) {
        int g = m >> 5, e = m & 31;
        *(float4*)&st3[g][e] = *(const float4*)(S + ((size_t)(bBase + g) * 4 + 3) * MEM + 72 + s * 32 + e);
    }
    __syncthreads();

    if (tid < 64) {
        int i = tid >> 3, k = tid & 7;
        float p1acc = 0.f, p2acc = 0.f;
        for (int g = 0; g < NG; g++) {
            sp2[g][tid] = p2acc;
            if (k == 0) sp1[g][i] = p1acc;
            if (s == 0) {
                size_t prow = (size_t)(bBase + g) * MEM;
                P[prow + 8 + tid] = p2acc;
                if (k == 0) P[prow + i] = p1acc;
            }
            p2acc += st2[g][tid] + p1acc * st1[g][k];
            p1acc += st1[g][i];
        }
    }
    __syncthreads();
    if (tid < 32) {
        int ijk = s * 32 + tid;
        int i = ijk >> 6, jk = ijk & 63, ij = ijk >> 3, k = ijk & 7;
        float acc3 = 0.f;
        for (int g = 0; g < NG; g++) {
            sp3[g][tid] = acc3;
            P[(size_t)(bBase + g) * MEM + 72 + ijk] = acc3;
            acc3 += st3[g][tid] + sp1[g][i] * st2[g][jk] + sp2[g][ij] * st1[g][k];
        }
    }
    __syncthreads();
    {
        const int i  = s >> 1;                 // m >> 9, constant per block
        const int ij = (s << 2) + (tid >> 6);  // m >> 6
        const int kl = tid & 63, l = tid & 7, p3 = tid >> 3;
        float acc4 = 0.f;
        size_t prowBase = (size_t)bBase * MEM + 584 + m4idx;
#pragma unroll
        for (int g = 0; g < NG; g++) {
            P[prowBase + (size_t)g * MEM] = acc4;
            acc4 += rL4[g] + sp1[g][i] * rL3[g] + sp2[g][ij] * st2[g][kl] + sp3[g][p3] * st1[g][l];
        }
    }
}

// ------------------------------------------------ kernel 3: per-chunk apply + log +
// pool. 1024 blocks = one per (b, chunk). Loads its snapshot into LDS; P fragments go
// straight to registers (each thread's P-slice is its own contiguous row). No fold
// recompute, no sP staging, no sQ23 buffer (q23 term inlined). LDS = 23.6 KB.
__global__ __launch_bounds__(256, 3) void apply_log_pool_kernel(const float* __restrict__ P,
                                                                const float* __restrict__ S,
                                                                float* __restrict__ partial) {
    int blk = blockIdx.x;                 // = (b*32+g)*4 + c = b*128 + n
    int tid = threadIdx.x;

    __shared__ __attribute__((aligned(16))) float sA[SIGSZ];
    __shared__ __attribute__((aligned(16))) float sR[648];   // L1 8 | L2 64 | L3 pad 576

    const float* Prow = P + (size_t)(blk >> 2) * MEM;
    const float* Srow = S + (size_t)blk * MEM;

    const int i1 = tid >> 6, j1 = (tid >> 3) & 7, k1 = tid & 7;
    const int row1 = tid >> 3, row2 = row1 + 32;
    const int jk = tid & 63;
    const int pos2 = tid + 256, i2 = pos2 >> 6;

    // P fragments -> registers (issued first; latency overlaps the LDS staging below).
    float a1  = Prow[i1],        a2  = Prow[8 + row1], a3  = Prow[72 + tid];
    float c1_ = Prow[i2],        c2_ = Prow[8 + row2], c3_ = Prow[72 + 256 + tid];
    float4 pa0 = *(const float4*)(Prow + 584 + tid * 8);
    float4 pa1 = *(const float4*)(Prow + 584 + tid * 8 + 4);
    float4 pb0 = *(const float4*)(Prow + 584 + (tid + 256) * 8);
    float4 pb1 = *(const float4*)(Prow + 584 + (tid + 256) * 8 + 4);

    // Stage the chunk-cumulative signature (unpadded global -> padded LDS).
    for (int m4 = tid * 4; m4 < MEM; m4 += 1024) {
        const float4 v = *(const float4*)(Srow + m4);
        float* d;
        if (m4 < 72) d = &sA[m4];
        else if (m4 < 584) { int e = m4 - 72;  d = &sA[P3OFF + (e >> 3) * 9 + (e & 7)]; }
        else               { int e = m4 - 584; d = &sA[P4OFF + (e >> 3) * 9 + (e & 7)]; }
        d[0] = v.x; d[1] = v.y; d[2] = v.z; d[3] = v.w;
    }
    __syncthreads();

    // R = ta_mul(P_group, A_chunk)  (full prefix signature for this chunk)
    const float* q3p = &sA[P3OFF + jk * 9];
    const float* q2p = &sA[8 + k1 * 8];
    float pP4a[8] = {pa0.x, pa0.y, pa0.z, pa0.w, pa1.x, pa1.y, pa1.z, pa1.w};
    float pP4b[8] = {pb0.x, pb0.y, pb0.z, pb0.w, pb1.x, pb1.y, pb1.z, pb1.w};
    float R4a[8], R4b[8];
#pragma unroll
    for (int l = 0; l < 8; l++) {
        float v3 = q3p[l], v2 = q2p[l], v1 = sA[l];
        R4a[l] = pP4a[l] + sA[P4OFF + tid * 9 + l]  + a1 * v3 + a2 * v2 + a3 * v1;
        R4b[l] = pP4b[l] + sA[P4OFF + pos2 * 9 + l] + c1_ * v3 + c2_ * v2 + c3_ * v1;
    }
    float R3a = a3  + sA[P3OFF + row1 * 9 + k1] + a1  * sA[8 + jk] + a2  * sA[k1];
    float R3b = c3_ + sA[P3OFF + row2 * 9 + k1] + c1_ * sA[8 + jk] + c2_ * sA[k1];
    float R2v = 0.f, R1v = 0.f;
    if (tid < 64) R2v = Prow[8 + tid] + sA[8 + tid] + Prow[tid >> 3] * sA[tid & 7];
    if (tid < 8)  R1v = Prow[tid] + sA[tid];

    sR[P3OFF + row1 * 9 + k1] = R3a;
    sR[P3OFF + row2 * 9 + k1] = R3b;
    if (tid < 64) sR[8 + tid] = R2v;
    if (tid < 8)  sR[tid] = R1v;
    __syncthreads();

    // log series, pooled. q23[r*9+c] = sR[r>>3]*sR[8+(r&7)*8+c] + sR[8+r]*sR[c];
    // for row jk that is s1j*r2p[l] + sR[8+jk]*s1l — inlined, no sQ23 buffer.
    float q23a = sR[i1] * sR[8 + jk] + sR[8 + row1] * sR[k1];
    float q23b = sR[i2] * sR[8 + jk] + sR[8 + row2] * sR[k1];
    float pool4a[8], pool4b[8];
    float pool3a, pool3b, pool2 = 0.f, pool1 = 0.f;
    {
        float s1ia = sR[i1], s1ib = sR[i2], s1j = sR[j1], s1k = sR[k1];
        float s2ija = sR[8 + row1], s2ijb = sR[8 + row2];
        float s2jk = sR[8 + jk];
        const float* r3p = &sR[P3OFF + jk * 9];
        const float* r2p = &sR[8 + k1 * 8];
#pragma unroll
        for (int l = 0; l < 8; l++) {
            float s1l = sR[l];
            float p22 = s1k * s1l;
            float q23l = s1j * r2p[l] + s2jk * s1l;
            float p24a = s1ia * r3p[l] + s2ija * r2p[l] + R3a * s1l;
            float p24b = s1ib * r3p[l] + s2ijb * r2p[l] + R3b * s1l;
            float p34a = s1ia * q23l + s2ija * p22;
            float p34b = s1ib * q23l + s2ijb * p22;
            float p44a = s1ia * s1j * p22;
            float p44b = s1ib * s1j * p22;
            pool4a[l] = R4a[l] - 0.5f * p24a + (1.f/3.f) * p34a - 0.25f * p44a;
            pool4b[l] = R4b[l] - 0.5f * p24b + (1.f/3.f) * p34b - 0.25f * p44b;
        }
        pool3a = R3a - 0.5f * q23a + (1.f/3.f) * s1ia * s1j * s1k;
        pool3b = R3b - 0.5f * q23b + (1.f/3.f) * s1ib * s1j * s1k;
        if (tid < 64) pool2 = R2v - 0.5f * sR[tid >> 3] * sR[tid & 7];
        if (tid < 8)  pool1 = R1v;
    }

    // plain coalesced stores; one fully-written row per chunk (NO atomics)
    {
        float* pb = partial + (size_t)blk * MEM;
        *(float4*)(pb + 584 + tid * 8)     = make_float4(pool4a[0], pool4a[1], pool4a[2], pool4a[3]);
        *(float4*)(pb + 584 + tid * 8 + 4) = make_float4(pool4a[4], pool4a[5], pool4a[6], pool4a[7]);
        *(float4*)(pb + 584 + (tid + 256) * 8)     = make_float4(pool4b[0], pool4b[1], pool4b[2], pool4b[3]);
        *(float4*)(pb + 584 + (tid + 256) * 8 + 4) = make_float4(pool4b[4], pool4b[5], pool4b[6], pool4b[7]);
        pb[72 + tid] = pool3a;
        pb[72 + 256 + tid] = pool3b;
        if (tid < 64) pb[8 + tid] = pool2;
        if (tid < 8)  pb[tid] = pool1;
    }
}

// ------------------------------------------------ kernel 4: reduce 128 partial rows
// per batch + gemv -> hpart. Row order (g asc, c asc) matches the old summation order.
__global__ __launch_bounds__(256) void gemv1_kernel(const float* __restrict__ partial,
                                                    const float* __restrict__ W1,
                                                    float* __restrict__ hpart) {
    int kc = blockIdx.x;
    int tid = threadIdx.x;
    int k0 = kc * 32;
    __shared__ float sp[8][32];
    {
        int bb = tid >> 5, k = tid & 31;
        float sum = 0.f;
        if (k0 + k < MEM) {
            const float* pp = partial + (size_t)bb * 128 * MEM + k0 + k;
#pragma unroll 8
            for (int n = 0; n < 128; n++) sum += pp[(size_t)n * MEM];
        }
        sp[bb][k] = sum * (1.f / 128.f);
    }
    __syncthreads();
    float acc[8];
#pragma unroll
    for (int b = 0; b < 8; b++) acc[b] = 0.f;
    int kend = (k0 + 32 < MEM) ? 32 : (MEM - k0);
    for (int k = 0; k < kend; k++) {
        float wv = W1[(size_t)(k0 + k) * 256 + tid];
#pragma unroll
        for (int b = 0; b < 8; b++) acc[b] += sp[b][k] * wv;
    }
#pragma unroll
    for (int b = 0; b < 8; b++) hpart[(size_t)kc * 2048 + b * 256 + tid] = acc[b];
}

// ------------------------------------------------ kernel 5: reduce hpart + final MLP
__global__ __launch_bounds__(256) void final_kernel(const float* __restrict__ hpart,
                                                    const float* __restrict__ b1,
                                                    const float* __restrict__ W2,
                                                    const float* __restrict__ b2,
                                                    float* __restrict__ outp) {
    int b = blockIdx.x;
    int tid = threadIdx.x;
    float v = 0.f;
#pragma unroll 7
    for (int kc = 0; kc < 147; kc++) v += hpart[(size_t)kc * 2048 + b * 256 + tid];
    v += b1[tid];
    v = fmaxf(v, 0.f) * W2[tid];
    __shared__ float sRed[256];
    sRed[tid] = v;
    __syncthreads();
    for (int s = 128; s > 0; s >>= 1) {
        if (tid < s) sRed[tid] += sRed[tid + s];
        __syncthreads();
    }
    if (tid == 0) outp[b] = sRed[0] + b2[0];
}

// ------------------------------------------------ launch
extern "C" void kernel_launch(void* const* d_in, const int* in_sizes, int n_in,
                              void* d_out, int out_size, void* d_ws, size_t ws_size,
                              hipStream_t stream) {
    const float* x  = (const float*)d_in[0];
    const float* W1 = (const float*)d_in[1];
    const float* b1 = (const float*)d_in[2];
    const float* W2 = (const float*)d_in[3];
    const float* b2 = (const float*)d_in[4];
    float* out = (float*)d_out;

    float* ws = (float*)d_ws;
    float* S       = ws;                             // 1024*MEM (per-chunk cumulative sigs; c=3 = totals)
    float* P       = S + (size_t)1024 * MEM;         // 256*MEM  (exclusive group prefixes)
    float* partial = P + (size_t)256 * MEM;          // 1024*MEM (per-chunk pooled rows, fully written)
    float* hpart   = partial + (size_t)1024 * MEM;   // 147*2048 (gemv partials, fully written)

    sig_totals_kernel<<<256, 256, 0, stream>>>(x, S);
    scan_fused_kernel<<<128, 256, 0, stream>>>(S, P);
    apply_log_pool_kernel<<<1024, 256, 0, stream>>>(P, S, partial);
    gemv1_kernel<<<147, 256, 0, stream>>>(partial, W1, hpart);
    final_kernel<<<8, 256, 0, stream>>>(hpart, b1, W2, b2, out);
}